// Round 1
// baseline (202.990 us; speedup 1.0000x reference)
//
#include <hip/hip_runtime.h>

// YOLOv1-style loss: S=7, B=2, C=20, L=49.
// preds row: [ pcls: L*C=980 | pconf: L*B=98 | pbox: L*B*4=392 ] = 1470 floats
// labels row: L * [ obj(1) | tcls(20) | tbox(4) ] = 1225 floats
// Loss weights: NOOBJ=0.5, OBJ=0.5, CLS=0.5, COORD=2.5

#define L_CELLS 49
#define PRED_ROW 1470
#define LAB_ROW 1225
#define CONF_BASE 980
#define BOX_BASE 1078
#define W_NOOBJ 0.5f
#define W_OBJ 0.5f
#define W_CLS 0.5f
#define W_COORD 2.5f
#define INV_S (1.0f / 7.0f)

__global__ void zero_out_kernel(float* out) { out[0] = 0.0f; }

__global__ __launch_bounds__(256) void yolo_loss_kernel(
    const float* __restrict__ preds, const float* __restrict__ labels,
    float* __restrict__ out, int n) {
  int cell = blockIdx.x * blockDim.x + threadIdx.x;
  int total = n * L_CELLS;
  float acc = 0.0f;
  if (cell < total) {
    int sample = cell / L_CELLS;
    int l = cell - sample * L_CELLS;
    const float* rp = preds + (size_t)sample * PRED_ROW;
    const float* labc = labels + (size_t)sample * LAB_ROW + l * 25;

    float objf = labc[0];
    const float* confp = rp + CONF_BASE + l * 2;
    float c0 = confp[0];
    float c1 = confp[1];

    if (objf != 0.0f) {
      // ---- full path (~15% of cells) ----
      const float* boxp = rp + BOX_BASE + l * 8;
      float bx[8];
#pragma unroll
      for (int k = 0; k < 8; ++k) bx[k] = boxp[k];

      float tx = labc[21], ty = labc[22], tw = labc[23], th = labc[24];
      float t0 = tx * INV_S, t1 = ty * INV_S, t2 = tw, t3 = th;

      float iou[2], rmse2[2];
#pragma unroll
      for (int b = 0; b < 2; ++b) {
        float o0 = bx[4 * b + 0] * INV_S;
        float o1 = bx[4 * b + 1] * INV_S;
        float o2 = bx[4 * b + 2] * bx[4 * b + 2];
        float o3 = bx[4 * b + 3] * bx[4 * b + 3];
        float left = fmaxf(t0 - 0.5f * t2, o0 - 0.5f * o2);
        float right = fminf(t0 + 0.5f * t2, o0 + 0.5f * o2);
        float top = fmaxf(t1 - 0.5f * t3, o1 - 0.5f * o3);
        float bot = fminf(t1 + 0.5f * t3, o1 + 0.5f * o3);
        float w = right - left;
        float h = bot - top;
        bool invalid = (w < 0.0f) || (h < 0.0f);
        float inter = invalid ? 0.0f : w * h;
        float uni = t2 * t3 + o2 * o3 - inter;
        iou[b] = invalid ? 0.0f : inter / fmaxf(uni, 1e-12f);
        float d0 = t0 - o0, d1 = t1 - o1, d2 = t2 - o2, d3 = t3 - o3;
        rmse2[b] = d0 * d0 + d1 * d1 + d2 * d2 + d3 * d3;  // sqrt monotone
      }

      float max_iou = fmaxf(iou[0], iou[1]);
      // jnp.argmax / argmin: first index wins ties -> strict compares for idx 1
      int best;
      if (max_iou > 0.0f)
        best = (iou[1] > iou[0]) ? 1 : 0;
      else
        best = (rmse2[1] < rmse2[0]) ? 1 : 0;
      float best_iou = iou[best];

      // conf: best box gets OBJ*(best_iou - conf)^2, other gets NOOBJ*conf^2
      float cb = (best == 0) ? c0 : c1;
      float co = (best == 0) ? c1 : c0;
      float db = best_iou - cb;
      acc += W_OBJ * db * db + W_NOOBJ * co * co;

      // cls
      const float* pcls = rp + l * 20;
      float clsacc = 0.0f;
#pragma unroll
      for (int c = 0; c < 20; ++c) {
        float d = labc[1 + c] - pcls[c];
        clsacc += d * d;
      }
      acc += W_CLS * clsacc;

      // coord: target (tx, ty, sqrt(tw), sqrt(th)) vs best raw box
      float e0 = tx - bx[best * 4 + 0];
      float e1 = ty - bx[best * 4 + 1];
      float e2 = sqrtf(tw) - bx[best * 4 + 2];
      float e3 = sqrtf(th) - bx[best * 4 + 3];
      acc += W_COORD * (e0 * e0 + e1 * e1 + e2 * e2 + e3 * e3);
    } else {
      // ---- no-obj path (~85%): only conf penalty ----
      acc = W_NOOBJ * (c0 * c0 + c1 * c1);
    }
  }

  // wave(64) shuffle reduction
#pragma unroll
  for (int off = 32; off > 0; off >>= 1) acc += __shfl_down(acc, off);

  __shared__ float wsum[4];  // 256 threads = 4 waves
  int wave = threadIdx.x >> 6;
  int lane = threadIdx.x & 63;
  if (lane == 0) wsum[wave] = acc;
  __syncthreads();
  if (threadIdx.x == 0) {
    float s = wsum[0] + wsum[1] + wsum[2] + wsum[3];
    atomicAdd(out, s);  // device-scope, one per block (3136 total)
  }
}

extern "C" void kernel_launch(void* const* d_in, const int* in_sizes, int n_in,
                              void* d_out, int out_size, void* d_ws, size_t ws_size,
                              hipStream_t stream) {
  const float* preds = (const float*)d_in[0];
  const float* labels = (const float*)d_in[1];
  float* out = (float*)d_out;
  int n = in_sizes[0] / PRED_ROW;  // 16384
  int total = n * L_CELLS;         // 802816
  int blocks = (total + 255) / 256;  // 3136

  zero_out_kernel<<<1, 1, 0, stream>>>(out);
  yolo_loss_kernel<<<blocks, 256, 0, stream>>>(preds, labels, out, n);
}